// Round 1
// baseline (347.103 us; speedup 1.0000x reference)
//
#include <hip/hip_runtime.h>
#include <hip/hip_bf16.h>

#define B_ 8
#define N_ 1024
#define H_ 8
#define D_ 64

typedef __attribute__((ext_vector_type(8))) short short8;
typedef __attribute__((ext_vector_type(4))) float f32x4;

// global -> LDS direct copy, 16 B per lane, linear LDS dest (wave-uniform base
// + lane*16); the XOR swizzle is applied on the GLOBAL source address (G21).
#define GLL(g, l)                                                         \
    __builtin_amdgcn_global_load_lds(                                     \
        (const __attribute__((address_space(1))) unsigned int*)(g),       \
        (__attribute__((address_space(3))) unsigned int*)(l), 16, 0, 0)

// ---------------------------------------------------------------------------
// k_prep: one block per (b,h), 1024 threads.  Pass 1: thread group (ng, dq)
// covers 16 rows x 4 dims -> column sum-of-squares partials (LDS reduce, no
// atomics) + row-normalized bf16 w_unit (16-lane shfl row ssq).  Pass 2 (rows
// L2-hot): energy[n] = sum_d q^2 / max(colsum_d, 1e-24).
// ---------------------------------------------------------------------------
__global__ __launch_bounds__(1024) void k_prep(const float* __restrict__ q,
                                               ushort* __restrict__ wunit,
                                               float* __restrict__ energy) {
    const int bh = blockIdx.x;
    const int b = bh >> 3, h = bh & 7;
    const float* qb = q + (size_t)(b * N_ * H_ + h) * D_;
    __shared__ float red[64][68];   // stride 68: breaks bank alignment
    __shared__ float inv2[64];
    const int t = threadIdx.x;
    const int ng = t >> 4;          // 64 row-groups
    const int dq = (t & 15) * 4;    // 4 consecutive d per thread
    float cx = 0.f, cy = 0.f, cz = 0.f, cw = 0.f;
    #pragma unroll
    for (int i = 0; i < 16; ++i) {
        const int n = i * 64 + ng;
        const float4 v = *(const float4*)(qb + (size_t)n * (H_ * D_) + dq);
        cx += v.x * v.x; cy += v.y * v.y; cz += v.z * v.z; cw += v.w * v.w;
        float ss = v.x * v.x + v.y * v.y + v.z * v.z + v.w * v.w;
        ss += __shfl_xor(ss, 1, 16);
        ss += __shfl_xor(ss, 2, 16);
        ss += __shfl_xor(ss, 4, 16);
        ss += __shfl_xor(ss, 8, 16);
        const float invr = 1.0f / fmaxf(sqrtf(ss), 1e-12f);
        __hip_bfloat162 p0 =
            __float22bfloat162_rn(make_float2(v.x * invr, v.y * invr));
        __hip_bfloat162 p1 =
            __float22bfloat162_rn(make_float2(v.z * invr, v.w * invr));
        uint2 pk;
        pk.x = *(unsigned int*)&p0;
        pk.y = *(unsigned int*)&p1;
        *(uint2*)(wunit + ((size_t)bh * N_ + n) * D_ + dq) = pk;
    }
    *(float4*)&red[ng][dq] = make_float4(cx, cy, cz, cw);
    __syncthreads();
    if (t < 64) {
        float s = 0.f;
        #pragma unroll
        for (int i = 0; i < 64; ++i) s += red[i][t];
        inv2[t] = 1.0f / fmaxf(s, 1e-24f);
    }
    __syncthreads();
    // pass 2: one row per thread (re-read hits L2: 262 KB/block, 2 MB/XCD)
    const float4* row = (const float4*)(qb + (size_t)t * (H_ * D_));
    float e = 0.f;
    #pragma unroll
    for (int i = 0; i < 16; ++i) {
        const float4 v = row[i];
        e += v.x * v.x * inv2[4 * i + 0] + v.y * v.y * inv2[4 * i + 1] +
             v.z * v.z * inv2[4 * i + 2] + v.w * v.w * inv2[4 * i + 3];
    }
    energy[(size_t)bh * N_ + t] = e;
}

// ---------------------------------------------------------------------------
// k_pi: softmax over head dim per (b,n).  No atomics (Pisum moved to k_out).
// ---------------------------------------------------------------------------
__global__ __launch_bounds__(256) void k_pi(const float* __restrict__ energy,
                                            const float* __restrict__ temp,
                                            float* __restrict__ Pi) {
    const int idx = blockIdx.x * 256 + threadIdx.x;  // [0, B*N)
    const int b = idx >> 10, n = idx & (N_ - 1);
    float e[H_];
    float m = -1e30f;
    #pragma unroll
    for (int h = 0; h < H_; ++h) {
        e[h] = energy[(size_t)(b * H_ + h) * N_ + n] * temp[h];
        m = fmaxf(m, e[h]);
    }
    float s = 0.f;
    #pragma unroll
    for (int h = 0; h < H_; ++h) { e[h] = expf(e[h] - m); s += e[h]; }
    const float inv = 1.0f / s;
    #pragma unroll
    for (int h = 0; h < H_; ++h)
        Pi[(size_t)(b * H_ + h) * N_ + n] = e[h] * inv;
}

// ---------------------------------------------------------------------------
// k_out: one block per (b,h), 1024 threads.  Fuses dots + Pisum + attnv +
// outw.  Pass 1: dots partials + Pisum (LDS reduce).  Then attnv in LDS.
// Pass 2: out0 row = -(q*Pi)*attnv, nontemporal (streaming, no reuse).
// ---------------------------------------------------------------------------
__global__ __launch_bounds__(1024) void k_out(const float* __restrict__ q,
                                              const float* __restrict__ Pi,
                                              float* __restrict__ out0) {
    const int bh = blockIdx.x;
    const int b = bh >> 3, h = bh & 7;
    const float* qb = q + (size_t)(b * N_ * H_ + h) * D_;
    const float* Pib = Pi + (size_t)bh * N_;
    __shared__ float red[64][68];
    __shared__ float redP[64];
    __shared__ float av[64];
    __shared__ float sInv;
    const int t = threadIdx.x;
    const int ng = t >> 4;
    const int dq = (t & 15) * 4;
    float cx = 0.f, cy = 0.f, cz = 0.f, cw = 0.f, ps = 0.f;
    #pragma unroll
    for (int i = 0; i < 16; ++i) {
        const int n = i * 64 + ng;
        const float p = Pib[n];
        const float4 v = *(const float4*)(qb + (size_t)n * (H_ * D_) + dq);
        cx += p * v.x * v.x; cy += p * v.y * v.y;
        cz += p * v.z * v.z; cw += p * v.w * v.w;
        ps += p;
    }
    *(float4*)&red[ng][dq] = make_float4(cx, cy, cz, cw);
    if ((t & 15) == 0) redP[ng] = ps;
    __syncthreads();
    float dsum = 0.f;
    if (t < 64) {
        #pragma unroll
        for (int i = 0; i < 64; ++i) dsum += red[i][t];
    }
    if (t == 0) {
        float S = 0.f;
        #pragma unroll
        for (int i = 0; i < 64; ++i) S += redP[i];
        sInv = 1.0f / (S + 1e-8f);
    }
    __syncthreads();
    if (t < 64) av[t] = 1.0f / (1.0f + dsum * sInv);
    __syncthreads();
    // pass 2: one row per thread
    const float p = -Pib[t];
    const float4* row = (const float4*)(qb + (size_t)t * (H_ * D_));
    f32x4* orow = (f32x4*)(out0 + ((size_t)(b * N_ + t) * H_ + h) * D_);
    #pragma unroll
    for (int i = 0; i < 16; ++i) {
        const float4 v = row[i];
        f32x4 o = {v.x * p * av[4 * i + 0], v.y * p * av[4 * i + 1],
                   v.z * p * av[4 * i + 2], v.w * p * av[4 * i + 3]};
        __builtin_nontemporal_store(o, orow + i);
    }
}

// ---------------------------------------------------------------------------
// k_gram v2: one block per (b, 32-row slab) -> 256 blocks = 1/CU, 512 thr
// (8 waves as 2M x 4N; wave tile 16 rows x 256 cols).  The FULL wunit[b,h]
// panel (1024x64 bf16 = 128 KB) lives in LDS, XOR-swizzled (granule ^= row&7)
// to kill the D=128B-stride bank conflict; loaded via global_load_lds with
// the inverse swizzle applied to the global source address.  h loops inside
// the block, so each block writes a CONTIGUOUS 1 MB region of out1 (rows
// n0..n0+31, all h, all m) in 1 KB-per-instruction nontemporal stores.
// blockIdx.x = b -> XCD affinity: per-XCD L2 keeps its 1 MB panel resident.
// ---------------------------------------------------------------------------
__global__ __launch_bounds__(512) void k_gram(const ushort* __restrict__ wunit,
                                              float* __restrict__ out1) {
    const int b = blockIdx.x;       // 0..7 (round-robin -> XCD b)
    const int slab = blockIdx.y;    // 0..31
    __shared__ __align__(16) char smem[133120];  // panel 131072 / staging 133120
    const int t = threadIdx.x;
    const int lane = t & 63, wave = t >> 6;
    const int wm = wave >> 2, wn = wave & 3;
    const int arow = lane & 15;
    const int lsel = lane >> 4;     // 0..3 -> k-granule select
    const int sw = arow & 7;        // row&7 swizzle bits (rows == arow mod 8)
    float* stgw = (float*)smem + wave * (16 * 260);  // per-wave staging

    #pragma unroll 1
    for (int h = 0; h < H_; ++h) {
        const char* Ubh =
            (const char*)(wunit + (size_t)(b * H_ + h) * N_ * D_);
        // ---- panel load: 8192 granules of 16 B, linear LDS dest ----
        #pragma unroll
        for (int k = 0; k < 16; ++k) {
            const int g_lin = k * 512 + t;
            const int row = g_lin >> 3;
            const int gsrc = (g_lin & 7) ^ (row & 7);  // inverse swizzle on src
            GLL(Ubh + row * 128 + gsrc * 16, smem + g_lin * 16);
        }
        __syncthreads();
        // ---- compute: 16x256 per wave, K=64 ----
        f32x4 acc[16];
        #pragma unroll
        for (int i = 0; i < 16; ++i) acc[i] = (f32x4){0.f, 0.f, 0.f, 0.f};
        #pragma unroll
        for (int kk = 0; kk < 2; ++kk) {
            const int go = ((lsel + kk * 4) ^ sw) << 4;  // swizzled granule
            const int rA = slab * 32 + wm * 16 + arow;
            const short8 a = *(const short8*)(smem + rA * 128 + go);
            #pragma unroll
            for (int tc = 0; tc < 16; ++tc) {
                const int rB = wn * 256 + tc * 16 + arow;
                const short8 bv = *(const short8*)(smem + rB * 128 + go);
                acc[tc] = __builtin_amdgcn_mfma_f32_16x16x32_bf16(
                    a, bv, acc[tc], 0, 0, 0);
            }
        }
        __syncthreads();  // all waves done reading panel before staging
        // ---- stage (stride 260 floats: 2-way bank alias only) + store ----
        const int rq = lsel * 4;
        #pragma unroll
        for (int tc = 0; tc < 16; ++tc)
            #pragma unroll
            for (int r = 0; r < 4; ++r)
                stgw[(rq + r) * 260 + tc * 16 + arow] =
                    (acc[tc][r] + 1.0f) * 0.5f;
        // in-wave DS write->read ordering via lgkmcnt; staging is wave-private
        #pragma unroll
        for (int r2 = 0; r2 < 16; ++r2) {
            const int n = slab * 32 + wm * 16 + r2;
            const f32x4 v = *(const f32x4*)(stgw + r2 * 260 + lane * 4);
            __builtin_nontemporal_store(
                v, (f32x4*)(out1 + ((size_t)(b * N_ + n) * H_ + h) * N_ +
                            wn * 256) + lane);
        }
        __syncthreads();  // staging reads done before next-h panel load
    }
}

// ---------------------------------------------------------------------------
extern "C" void kernel_launch(void* const* d_in, const int* in_sizes, int n_in,
                              void* d_out, int out_size, void* d_ws,
                              size_t ws_size, hipStream_t stream) {
    const float* q = (const float*)d_in[0];     // [B, N, H, D] fp32
    const float* temp = (const float*)d_in[1];  // [H] fp32
    float* out0 = (float*)d_out;                       // [B,N,H,D]
    float* out1 = out0 + (size_t)B_ * N_ * H_ * D_;    // [B,N,H,N]

    char* ws = (char*)d_ws;
    ushort* wunit = (ushort*)ws;                 // 8,388,608 B
    float* Pi     = (float*)(ws + 8388608);      //   262,144 B
    float* energy = (float*)(ws + 8650752);      //   262,144 B

    k_prep<<<64, 1024, 0, stream>>>(q, wunit, energy);
    k_pi<<<32, 256, 0, stream>>>(energy, temp, Pi);
    k_out<<<64, 1024, 0, stream>>>(q, Pi, out0);
    k_gram<<<dim3(8, 32), 512, 0, stream>>>(wunit, out1);
}